// Round 1
// baseline (905.722 us; speedup 1.0000x reference)
//
#include <hip/hip_runtime.h>
#include <math.h>

// Problem constants: B=1, L=512, C_S=384, H=12, D=32
// ws layout (floats):
//   q_ws    : 512*384            = 196608
//   kv_ws   : 512*768            = 393216
//   o_ws    : 512*384            = 196608
//   bias_ws : 12*512*512         = 3145728   [h][i][j]
//   gate_ws : 12*512*512         = 3145728   [h][i][j] (already sigmoid'ed)
// total = 7077888 floats = 28.3 MB (assumed <= ws_size)

// ---------------------------------------------------------------------------
// Generic small SGEMM: C[M x N] = A[M x K] @ B[K x N] + bias (row-major).
// Tile 32(M) x 64(N), K-chunk 32, 256 threads, 2x4 micro-tile.
// M multiple of 32, N multiple of 64, K multiple of 32 (all true here).
// ---------------------------------------------------------------------------
__global__ __launch_bounds__(256) void sgemm_bias(const float* __restrict__ A, int lda,
                                                  const float* __restrict__ B, int ldb,
                                                  const float* __restrict__ bias,
                                                  float* __restrict__ C, int ldc, int K)
{
    __shared__ float As[32 * 36];   // [k][m], stride 36 (pad for bank spread)
    __shared__ float Bs[32 * 68];   // [k][n], stride 68

    const int t  = threadIdx.x;
    const int m0 = blockIdx.y * 32;
    const int n0 = blockIdx.x * 64;
    const int tx = t & 15;          // n micro (4 cols)
    const int ty = t >> 4;          // m micro (2 rows)

    float acc[2][4];
    #pragma unroll
    for (int i = 0; i < 2; ++i)
        #pragma unroll
        for (int j = 0; j < 4; ++j) acc[i][j] = 0.f;

    for (int kc = 0; kc < K; kc += 32) {
        __syncthreads();
        // stage A tile (32 rows x 32 k), one float4 per thread, store transposed
        {
            int r = t >> 3, c = (t & 7) * 4;
            float4 av = *(const float4*)&A[(size_t)(m0 + r) * lda + kc + c];
            As[(c + 0) * 36 + r] = av.x;
            As[(c + 1) * 36 + r] = av.y;
            As[(c + 2) * 36 + r] = av.z;
            As[(c + 3) * 36 + r] = av.w;
        }
        // stage B tile (32 k x 64 n), two float4 per thread
        #pragma unroll
        for (int i = 0; i < 2; ++i) {
            int slot = i * 256 + t;
            int r = slot >> 4, c = (slot & 15) * 4;
            *(float4*)&Bs[r * 68 + c] = *(const float4*)&B[(size_t)(kc + r) * ldb + n0 + c];
        }
        __syncthreads();
        #pragma unroll 8
        for (int k = 0; k < 32; ++k) {
            float2 a = *(const float2*)&As[k * 36 + ty * 2];
            float4 b = *(const float4*)&Bs[k * 68 + tx * 4];
            acc[0][0] = fmaf(a.x, b.x, acc[0][0]);
            acc[0][1] = fmaf(a.x, b.y, acc[0][1]);
            acc[0][2] = fmaf(a.x, b.z, acc[0][2]);
            acc[0][3] = fmaf(a.x, b.w, acc[0][3]);
            acc[1][0] = fmaf(a.y, b.x, acc[1][0]);
            acc[1][1] = fmaf(a.y, b.y, acc[1][1]);
            acc[1][2] = fmaf(a.y, b.z, acc[1][2]);
            acc[1][3] = fmaf(a.y, b.w, acc[1][3]);
        }
    }

    float4 bv = *(const float4*)&bias[n0 + tx * 4];
    #pragma unroll
    for (int im = 0; im < 2; ++im) {
        float4 r;
        r.x = acc[im][0] + bv.x;
        r.y = acc[im][1] + bv.y;
        r.z = acc[im][2] + bv.z;
        r.w = acc[im][3] + bv.w;
        *(float4*)&C[(size_t)(m0 + ty * 2 + im) * ldc + n0 + tx * 4] = r;
    }
}

// ---------------------------------------------------------------------------
// bias/gate streaming kernel: the 402 MB z read.
// One thread per (i,j) pair; block = 256 pairs. K-loop in chunks of 32 with
// register double-buffered prefetch so HBM loads overlap compute.
// zt row stride 36: compute reads zt[t*36 + 4k] -> banks (4t+4k)%32,
// conflict-free for ds_read_b128. W chunk is wave-uniform -> LDS broadcast.
// ---------------------------------------------------------------------------
__global__ __launch_bounds__(256, 4) void biasgate_kernel(const float* __restrict__ z,
                                                          const float* __restrict__ Wb,
                                                          const float* __restrict__ bb,
                                                          const float* __restrict__ Wg,
                                                          const float* __restrict__ bg,
                                                          float* __restrict__ bias_out,
                                                          float* __restrict__ gate_out)
{
    __shared__ float zt[256 * 36];  // 36 KB: 256 pairs x 32 k (pad to 36)
    __shared__ float wt[768];       // 3 KB: [24 h][32 k] chunk of W^T (Wb|Wg)

    const int t = threadIdx.x;
    const size_t p0 = (size_t)blockIdx.x * 256;

    float acc[24];
    #pragma unroll
    for (int h = 0; h < 24; ++h) acc[h] = 0.f;

    // prefetch chunk 0 into registers (8 x float4 = this block's 256x32 tile share)
    float4 r[8];
    #pragma unroll
    for (int i = 0; i < 8; ++i) {
        int slot = i * 256 + t;
        int row = slot >> 3, col = (slot & 7) * 4;
        r[i] = *(const float4*)&z[(p0 + row) * 384 + col];
    }

    for (int c = 0; c < 12; ++c) {
        const int kc = c * 32;
        __syncthreads();   // previous chunk's compute done -> safe to overwrite LDS
        // stage W^T chunk: wt[h*32+k] = W[kc+k][h]  (tiny, L2-resident)
        #pragma unroll
        for (int i = 0; i < 3; ++i) {
            int idx = t + i * 256;
            int hh = idx >> 5, kk = idx & 31;
            wt[idx] = (hh < 12) ? Wb[(kc + kk) * 12 + hh] : Wg[(kc + kk) * 12 + (hh - 12)];
        }
        // commit prefetched z tile to LDS
        #pragma unroll
        for (int i = 0; i < 8; ++i) {
            int slot = i * 256 + t;
            int row = slot >> 3, col = (slot & 7) * 4;
            *(float4*)&zt[row * 36 + col] = r[i];
        }
        // issue next chunk's global loads (in flight during compute below)
        if (c < 11) {
            const int kc2 = kc + 32;
            #pragma unroll
            for (int i = 0; i < 8; ++i) {
                int slot = i * 256 + t;
                int row = slot >> 3, col = (slot & 7) * 4;
                r[i] = *(const float4*)&z[(p0 + row) * 384 + kc2 + col];
            }
        }
        __syncthreads();
        // compute: 32 k x 24 h FMAs per thread
        #pragma unroll
        for (int k4 = 0; k4 < 8; ++k4) {
            float4 zv = *(const float4*)&zt[t * 36 + k4 * 4];
            #pragma unroll
            for (int hh = 0; hh < 24; ++hh) {
                float4 w = *(const float4*)&wt[hh * 32 + k4 * 4];   // broadcast
                acc[hh] = fmaf(zv.x, w.x, acc[hh]);
                acc[hh] = fmaf(zv.y, w.y, acc[hh]);
                acc[hh] = fmaf(zv.z, w.z, acc[hh]);
                acc[hh] = fmaf(zv.w, w.w, acc[hh]);
            }
        }
    }

    const size_t p = p0 + t;
    #pragma unroll
    for (int hh = 0; hh < 12; ++hh)
        bias_out[(size_t)hh * 262144 + p] = acc[hh] + bb[hh];
    #pragma unroll
    for (int hh = 0; hh < 12; ++hh) {
        float x = acc[12 + hh] + bg[hh];
        gate_out[(size_t)hh * 262144 + p] = 1.f / (1.f + expf(-x));
    }
}

// ---------------------------------------------------------------------------
// Attention: block = (h, 16 query rows). Full 16x512 logits tile in LDS.
//   A: logits = q.k/sqrt(D) + bias, masked     (k chunks of 128 in LDS)
//   B: softmax over j (16-lane shuffle groups) * gate
//   C: o = attn @ v   (v streamed via L1/L2, lanes = d -> coalesced)
// ---------------------------------------------------------------------------
__global__ __launch_bounds__(256) void attn_kernel(const float* __restrict__ q_ws,
                                                   const float* __restrict__ kv_ws,
                                                   const float* __restrict__ bias_ws,
                                                   const float* __restrict__ gate_ws,
                                                   const int* __restrict__ mask,
                                                   float* __restrict__ o_ws)
{
    __shared__ float ql[16 * 36];
    __shared__ float kl[128 * 36];
    __shared__ float att[16 * 516];   // row stride 516 (pad 4)
    __shared__ int   mint[16];

    const int t  = threadIdx.x;
    const int h  = blockIdx.y;
    const int i0 = blockIdx.x * 16;

    for (int idx = t; idx < 512; idx += 256) {
        int ii = idx >> 5, d = idx & 31;
        ql[ii * 36 + d] = q_ws[(size_t)(i0 + ii) * 384 + h * 32 + d];
    }
    if (t < 16) mint[t] = mask[i0 + t];

    const float inv = 0.17677669529663687f;   // 1/sqrt(32)
    const int jl = t & 127;
    const int ip = t >> 7;                     // 0 or 1

    // Phase A: logits
    for (int jc = 0; jc < 4; ++jc) {
        const int j0 = jc * 128;
        __syncthreads();   // protects kl restage (and covers ql/mint on iter 0)
        for (int idx = t; idx < 4096; idx += 256) {
            int jj = idx >> 5, d = idx & 31;
            kl[jj * 36 + d] = kv_ws[(size_t)(j0 + jj) * 768 + h * 32 + d];
        }
        __syncthreads();
        float4 kr[8];
        #pragma unroll
        for (int x = 0; x < 8; ++x) kr[x] = *(const float4*)&kl[jl * 36 + x * 4];
        const int mj = mask[j0 + jl];
        #pragma unroll
        for (int rr = 0; rr < 8; ++rr) {
            int ii = ip + rr * 2;
            float dot = 0.f;
            #pragma unroll
            for (int x = 0; x < 8; ++x) {
                float4 qv = *(const float4*)&ql[ii * 36 + x * 4];
                dot = fmaf(kr[x].x, qv.x, dot);
                dot = fmaf(kr[x].y, qv.y, dot);
                dot = fmaf(kr[x].z, qv.z, dot);
                dot = fmaf(kr[x].w, qv.w, dot);
            }
            float bv = bias_ws[((size_t)h << 18) + (size_t)(i0 + ii) * 512 + j0 + jl];
            float lg = fmaf(dot, inv, bv);
            att[ii * 516 + j0 + jl] = (mint[ii] != 0 && mj != 0) ? lg : -1e9f;
        }
    }
    __syncthreads();

    // Phase B: softmax * gate (row = t/16, 16 lanes per row, 32 elems each)
    {
        const int rr = t >> 4, g = t & 15;
        const int base = rr * 516 + g;
        float mx = -3.0e38f;
        #pragma unroll
        for (int n = 0; n < 32; ++n) mx = fmaxf(mx, att[base + n * 16]);
        #pragma unroll
        for (int off = 8; off >= 1; off >>= 1) mx = fmaxf(mx, __shfl_xor(mx, off));
        float sum = 0.f;
        #pragma unroll
        for (int n = 0; n < 32; ++n) {
            float e = expf(att[base + n * 16] - mx);
            att[base + n * 16] = e;
            sum += e;
        }
        #pragma unroll
        for (int off = 8; off >= 1; off >>= 1) sum += __shfl_xor(sum, off);
        float isum = 1.f / sum;
        const size_t gbase = ((size_t)h << 18) + (size_t)(i0 + rr) * 512 + g;
        #pragma unroll
        for (int n = 0; n < 32; ++n) {
            float gt = gate_ws[gbase + n * 16];
            att[base + n * 16] *= isum * gt;
        }
    }
    __syncthreads();

    // Phase C: o = attn @ v. thread = (group g = rows {g, g+8}, d)
    {
        const int d = t & 31, grp = t >> 5;
        const float* vp = kv_ws + 384 + h * 32 + d;
        float a0 = 0.f, a1 = 0.f;
        #pragma unroll 8
        for (int j = 0; j < 512; ++j) {
            float vv = vp[(size_t)j * 768];
            a0 = fmaf(att[grp * 516 + j], vv, a0);
            a1 = fmaf(att[(grp + 8) * 516 + j], vv, a1);
        }
        o_ws[(size_t)(i0 + grp) * 384 + h * 32 + d]     = a0;
        o_ws[(size_t)(i0 + grp + 8) * 384 + h * 32 + d] = a1;
    }
}

// ---------------------------------------------------------------------------
extern "C" void kernel_launch(void* const* d_in, const int* in_sizes, int n_in,
                              void* d_out, int out_size, void* d_ws, size_t ws_size,
                              hipStream_t stream)
{
    const float* s    = (const float*)d_in[0];
    const float* z    = (const float*)d_in[1];
    const int*   mask = (const int*)  d_in[2];
    const float* Wq   = (const float*)d_in[3];
    const float* bq   = (const float*)d_in[4];
    const float* Wkv  = (const float*)d_in[5];
    const float* bkv  = (const float*)d_in[6];
    const float* Wb   = (const float*)d_in[7];
    const float* bb   = (const float*)d_in[8];
    const float* Wg   = (const float*)d_in[9];
    const float* bg   = (const float*)d_in[10];
    const float* Wout = (const float*)d_in[11];
    const float* bout = (const float*)d_in[12];
    float* out = (float*)d_out;

    float* ws      = (float*)d_ws;
    float* q_ws    = ws;                          // 512*384
    float* kv_ws   = q_ws + 512 * 384;            // 512*768
    float* o_ws    = kv_ws + 512 * 768;           // 512*384
    float* bias_ws = o_ws + 512 * 384;            // 12*512*512
    float* gate_ws = bias_ws + 12 * 512 * 512;    // 12*512*512

    // q = s @ Wq + bq            (512x384 @ 384x384)
    sgemm_bias<<<dim3(384 / 64, 512 / 32), 256, 0, stream>>>(s, 384, Wq, 384, bq, q_ws, 384, 384);
    // kv = s @ Wkv + bkv         (512x384 @ 384x768)
    sgemm_bias<<<dim3(768 / 64, 512 / 32), 256, 0, stream>>>(s, 384, Wkv, 768, bkv, kv_ws, 768, 384);
    // bias/gate = z @ [Wb|Wg]    (the 402 MB stream)
    biasgate_kernel<<<1024, 256, 0, stream>>>(z, Wb, bb, Wg, bg, bias_ws, gate_ws);
    // attention
    attn_kernel<<<dim3(512 / 16, 12), 256, 0, stream>>>(q_ws, kv_ws, bias_ws, gate_ws, mask, o_ws);
    // out = o @ Wout + bout
    sgemm_bias<<<dim3(384 / 64, 512 / 32), 256, 0, stream>>>(o_ws, 384, Wout, 384, bout, out, 384, 384);
}

// Round 2
// 795.713 us; speedup vs baseline: 1.1383x; 1.1383x over previous
//
#include <hip/hip_runtime.h>
#include <math.h>

// Problem constants: B=1, L=512, C_S=384, H=12, D=32
// ws layout (floats):
//   q_ws    : 512*384            = 196608
//   kv_ws   : 512*768            = 393216
//   o_ws    : 512*384            = 196608
//   bias_ws : 12*512*512         = 3145728   [h][i][j]
//   gate_ws : 12*512*512         = 3145728   [h][i][j] (already sigmoid'ed)
//   wcat_ws : 24*384             = 9216      [h][k] transposed Wb|Wg
// total = 7087104 floats = 28.35 MB

// ---------------------------------------------------------------------------
// Generic small SGEMM: C[M x N] = A[M x K] @ B[K x N] + bias (row-major).
// Tile 32(M) x 64(N), K-chunk 32, 256 threads, 2x4 micro-tile.
// ---------------------------------------------------------------------------
__global__ __launch_bounds__(256) void sgemm_bias(const float* __restrict__ A, int lda,
                                                  const float* __restrict__ B, int ldb,
                                                  const float* __restrict__ bias,
                                                  float* __restrict__ C, int ldc, int K)
{
    __shared__ float As[32 * 36];   // [k][m], stride 36 (pad for bank spread)
    __shared__ float Bs[32 * 68];   // [k][n], stride 68

    const int t  = threadIdx.x;
    const int m0 = blockIdx.y * 32;
    const int n0 = blockIdx.x * 64;
    const int tx = t & 15;          // n micro (4 cols)
    const int ty = t >> 4;          // m micro (2 rows)

    float acc[2][4];
    #pragma unroll
    for (int i = 0; i < 2; ++i)
        #pragma unroll
        for (int j = 0; j < 4; ++j) acc[i][j] = 0.f;

    for (int kc = 0; kc < K; kc += 32) {
        __syncthreads();
        {
            int r = t >> 3, c = (t & 7) * 4;
            float4 av = *(const float4*)&A[(size_t)(m0 + r) * lda + kc + c];
            As[(c + 0) * 36 + r] = av.x;
            As[(c + 1) * 36 + r] = av.y;
            As[(c + 2) * 36 + r] = av.z;
            As[(c + 3) * 36 + r] = av.w;
        }
        #pragma unroll
        for (int i = 0; i < 2; ++i) {
            int slot = i * 256 + t;
            int r = slot >> 4, c = (slot & 15) * 4;
            *(float4*)&Bs[r * 68 + c] = *(const float4*)&B[(size_t)(kc + r) * ldb + n0 + c];
        }
        __syncthreads();
        #pragma unroll 8
        for (int k = 0; k < 32; ++k) {
            float2 a = *(const float2*)&As[k * 36 + ty * 2];
            float4 b = *(const float4*)&Bs[k * 68 + tx * 4];
            acc[0][0] = fmaf(a.x, b.x, acc[0][0]);
            acc[0][1] = fmaf(a.x, b.y, acc[0][1]);
            acc[0][2] = fmaf(a.x, b.z, acc[0][2]);
            acc[0][3] = fmaf(a.x, b.w, acc[0][3]);
            acc[1][0] = fmaf(a.y, b.x, acc[1][0]);
            acc[1][1] = fmaf(a.y, b.y, acc[1][1]);
            acc[1][2] = fmaf(a.y, b.z, acc[1][2]);
            acc[1][3] = fmaf(a.y, b.w, acc[1][3]);
        }
    }

    float4 bv = *(const float4*)&bias[n0 + tx * 4];
    #pragma unroll
    for (int im = 0; im < 2; ++im) {
        float4 r;
        r.x = acc[im][0] + bv.x;
        r.y = acc[im][1] + bv.y;
        r.z = acc[im][2] + bv.z;
        r.w = acc[im][3] + bv.w;
        *(float4*)&C[(size_t)(m0 + ty * 2 + im) * ldc + n0 + tx * 4] = r;
    }
}

// ---------------------------------------------------------------------------
// Tiny prep: wcat[h][k] = (h<12 ? Wb[k][h] : Wg[k][h-12]); transposed so the
// main kernel reads contiguous float4 along k at a wave-uniform address.
// ---------------------------------------------------------------------------
__global__ __launch_bounds__(256) void wcat_kernel(const float* __restrict__ Wb,
                                                   const float* __restrict__ Wg,
                                                   float* __restrict__ wcat)
{
    for (int idx = threadIdx.x; idx < 24 * 384; idx += 256) {
        int hh = idx / 384, k = idx % 384;
        wcat[idx] = (hh < 12) ? Wb[k * 12 + hh] : Wg[k * 12 + (hh - 12)];
    }
}

// ---------------------------------------------------------------------------
// bias/gate streaming kernel v2: the 402 MB z read.
// One thread per (i,j) pair. NO LDS, NO barriers, NO register prefetch:
//  - z: each thread consumes its own full 128 B cache lines (8 x float4 per
//    32-k chunk, batched so the line is pulled once and register pressure
//    stays at 32 VGPRs for the chunk).
//  - W: wave-uniform float4 loads from wcat (scalarizes to s_load; worst
//    case a single-line vector broadcast). Zero LDS traffic.
// Live set ~ acc[24] + zr[32] + addressing ~ 60 VGPRs -> no spill.
// ---------------------------------------------------------------------------
__global__ __launch_bounds__(256) void biasgate_kernel(const float* __restrict__ z,
                                                       const float* __restrict__ wcat,
                                                       const float* __restrict__ bb,
                                                       const float* __restrict__ bg,
                                                       float* __restrict__ bias_out,
                                                       float* __restrict__ gate_out)
{
    const int t = threadIdx.x;
    const size_t p = (size_t)blockIdx.x * 256 + t;
    const float* zp = z + p * 384;

    float acc[24];
    #pragma unroll
    for (int h = 0; h < 24; ++h) acc[h] = 0.f;

    for (int c = 0; c < 12; ++c) {
        const int kc = c * 32;
        float4 zr[8];
        #pragma unroll
        for (int i = 0; i < 8; ++i)
            zr[i] = *(const float4*)&zp[kc + i * 4];
        #pragma unroll
        for (int k4 = 0; k4 < 8; ++k4) {
            const float4 zv = zr[k4];
            const float* wp = wcat + kc + k4 * 4;
            #pragma unroll
            for (int hh = 0; hh < 24; ++hh) {
                float4 w = *(const float4*)&wp[hh * 384];   // wave-uniform
                acc[hh] = fmaf(zv.x, w.x,
                          fmaf(zv.y, w.y,
                          fmaf(zv.z, w.z,
                          fmaf(zv.w, w.w, acc[hh]))));
            }
        }
    }

    #pragma unroll
    for (int hh = 0; hh < 12; ++hh)
        bias_out[(size_t)hh * 262144 + p] = acc[hh] + bb[hh];
    #pragma unroll
    for (int hh = 0; hh < 12; ++hh) {
        float x = acc[12 + hh] + bg[hh];
        gate_out[(size_t)hh * 262144 + p] = 1.f / (1.f + expf(-x));
    }
}

// ---------------------------------------------------------------------------
// Attention: block = (h, 16 query rows). Full 16x512 logits tile in LDS.
// ---------------------------------------------------------------------------
__global__ __launch_bounds__(256) void attn_kernel(const float* __restrict__ q_ws,
                                                   const float* __restrict__ kv_ws,
                                                   const float* __restrict__ bias_ws,
                                                   const float* __restrict__ gate_ws,
                                                   const int* __restrict__ mask,
                                                   float* __restrict__ o_ws)
{
    __shared__ float ql[16 * 36];
    __shared__ float kl[128 * 36];
    __shared__ float att[16 * 516];   // row stride 516 (pad 4)
    __shared__ int   mint[16];

    const int t  = threadIdx.x;
    const int h  = blockIdx.y;
    const int i0 = blockIdx.x * 16;

    for (int idx = t; idx < 512; idx += 256) {
        int ii = idx >> 5, d = idx & 31;
        ql[ii * 36 + d] = q_ws[(size_t)(i0 + ii) * 384 + h * 32 + d];
    }
    if (t < 16) mint[t] = mask[i0 + t];

    const float inv = 0.17677669529663687f;   // 1/sqrt(32)
    const int jl = t & 127;
    const int ip = t >> 7;                     // 0 or 1

    // Phase A: logits
    for (int jc = 0; jc < 4; ++jc) {
        const int j0 = jc * 128;
        __syncthreads();
        for (int idx = t; idx < 4096; idx += 256) {
            int jj = idx >> 5, d = idx & 31;
            kl[jj * 36 + d] = kv_ws[(size_t)(j0 + jj) * 768 + h * 32 + d];
        }
        __syncthreads();
        float4 kr[8];
        #pragma unroll
        for (int x = 0; x < 8; ++x) kr[x] = *(const float4*)&kl[jl * 36 + x * 4];
        const int mj = mask[j0 + jl];
        #pragma unroll
        for (int rr = 0; rr < 8; ++rr) {
            int ii = ip + rr * 2;
            float dot = 0.f;
            #pragma unroll
            for (int x = 0; x < 8; ++x) {
                float4 qv = *(const float4*)&ql[ii * 36 + x * 4];
                dot = fmaf(kr[x].x, qv.x, dot);
                dot = fmaf(kr[x].y, qv.y, dot);
                dot = fmaf(kr[x].z, qv.z, dot);
                dot = fmaf(kr[x].w, qv.w, dot);
            }
            float bv = bias_ws[((size_t)h << 18) + (size_t)(i0 + ii) * 512 + j0 + jl];
            float lg = fmaf(dot, inv, bv);
            att[ii * 516 + j0 + jl] = (mint[ii] != 0 && mj != 0) ? lg : -1e9f;
        }
    }
    __syncthreads();

    // Phase B: softmax * gate (row = t/16, 16 lanes per row, 32 elems each)
    {
        const int rr = t >> 4, g = t & 15;
        const int base = rr * 516 + g;
        float mx = -3.0e38f;
        #pragma unroll
        for (int n = 0; n < 32; ++n) mx = fmaxf(mx, att[base + n * 16]);
        #pragma unroll
        for (int off = 8; off >= 1; off >>= 1) mx = fmaxf(mx, __shfl_xor(mx, off));
        float sum = 0.f;
        #pragma unroll
        for (int n = 0; n < 32; ++n) {
            float e = expf(att[base + n * 16] - mx);
            att[base + n * 16] = e;
            sum += e;
        }
        #pragma unroll
        for (int off = 8; off >= 1; off >>= 1) sum += __shfl_xor(sum, off);
        float isum = 1.f / sum;
        const size_t gbase = ((size_t)h << 18) + (size_t)(i0 + rr) * 512 + g;
        #pragma unroll
        for (int n = 0; n < 32; ++n) {
            float gt = gate_ws[gbase + n * 16];
            att[base + n * 16] *= isum * gt;
        }
    }
    __syncthreads();

    // Phase C: o = attn @ v. thread = (group g = rows {g, g+8}, d)
    {
        const int d = t & 31, grp = t >> 5;
        const float* vp = kv_ws + 384 + h * 32 + d;
        float a0 = 0.f, a1 = 0.f;
        #pragma unroll 8
        for (int j = 0; j < 512; ++j) {
            float vv = vp[(size_t)j * 768];
            a0 = fmaf(att[grp * 516 + j], vv, a0);
            a1 = fmaf(att[(grp + 8) * 516 + j], vv, a1);
        }
        o_ws[(size_t)(i0 + grp) * 384 + h * 32 + d]     = a0;
        o_ws[(size_t)(i0 + grp + 8) * 384 + h * 32 + d] = a1;
    }
}

// ---------------------------------------------------------------------------
extern "C" void kernel_launch(void* const* d_in, const int* in_sizes, int n_in,
                              void* d_out, int out_size, void* d_ws, size_t ws_size,
                              hipStream_t stream)
{
    const float* s    = (const float*)d_in[0];
    const float* z    = (const float*)d_in[1];
    const int*   mask = (const int*)  d_in[2];
    const float* Wq   = (const float*)d_in[3];
    const float* bq   = (const float*)d_in[4];
    const float* Wkv  = (const float*)d_in[5];
    const float* bkv  = (const float*)d_in[6];
    const float* Wb   = (const float*)d_in[7];
    const float* bb   = (const float*)d_in[8];
    const float* Wg   = (const float*)d_in[9];
    const float* bg   = (const float*)d_in[10];
    const float* Wout = (const float*)d_in[11];
    const float* bout = (const float*)d_in[12];
    float* out = (float*)d_out;

    float* ws      = (float*)d_ws;
    float* q_ws    = ws;                          // 512*384
    float* kv_ws   = q_ws + 512 * 384;            // 512*768
    float* o_ws    = kv_ws + 512 * 768;           // 512*384
    float* bias_ws = o_ws + 512 * 384;            // 12*512*512
    float* gate_ws = bias_ws + 12 * 512 * 512;    // 12*512*512
    float* wcat_ws = gate_ws + 12 * 512 * 512;    // 24*384

    // W transpose prep (tiny)
    wcat_kernel<<<1, 256, 0, stream>>>(Wb, Wg, wcat_ws);
    // q = s @ Wq + bq            (512x384 @ 384x384)
    sgemm_bias<<<dim3(384 / 64, 512 / 32), 256, 0, stream>>>(s, 384, Wq, 384, bq, q_ws, 384, 384);
    // kv = s @ Wkv + bkv         (512x384 @ 384x768)
    sgemm_bias<<<dim3(768 / 64, 512 / 32), 256, 0, stream>>>(s, 384, Wkv, 768, bkv, kv_ws, 768, 384);
    // bias/gate = z @ [Wb|Wg]    (the 402 MB stream)
    biasgate_kernel<<<1024, 256, 0, stream>>>(z, wcat_ws, bb, bg, bias_ws, gate_ws);
    // attention
    attn_kernel<<<dim3(512 / 16, 12), 256, 0, stream>>>(q_ws, kv_ws, bias_ws, gate_ws, mask, o_ws);
    // out = o @ Wout + bout
    sgemm_bias<<<dim3(384 / 64, 512 / 32), 256, 0, stream>>>(o_ws, 384, Wout, 384, bout, out, 384, 384);
}